// Round 6
// baseline (12824.376 us; speedup 1.0000x reference)
//
#include <hip/hip_runtime.h>

typedef _Float16 f16;
typedef _Float16 f16x4 __attribute__((ext_vector_type(4)));
typedef _Float16 f16x8 __attribute__((ext_vector_type(8)));
typedef float f32x4 __attribute__((ext_vector_type(4)));
typedef unsigned u32x4 __attribute__((ext_vector_type(4)));

#define SEQ 4096
#define NF  2048
#define HID 1024

// ---------------- static device scratch ----------------
__device__ f16   g_Ahi[SEQ * NF];
__device__ f16   g_Alo[SEQ * NF];
__device__ f16   g_Whi[2 * 4096 * NF];
__device__ f16   g_Wlo[2 * 4096 * NF];
__device__ float g_xp [2u * SEQ * 4096u];          // [dir][t][4096]
__device__ float g_hist[2u * SEQ * HID];           // [dir][t][1024]
__device__ unsigned long long g_ring[2][2][1024];  // [dir][slot][j] = tag<<32 | h_bits
__device__ float g_feats[SEQ * 10];

// ---------------- fp32 -> f16 hi/lo split ----------------
__global__ void cvt_split(const float* __restrict__ src, int which, int n4) {
  int i = blockIdx.x * blockDim.x + threadIdx.x;
  int stride = gridDim.x * blockDim.x;
  f16* hi; f16* lo;
  if (which == 0)      { hi = g_Ahi; lo = g_Alo; }
  else if (which == 1) { hi = g_Whi; lo = g_Wlo; }
  else                 { hi = g_Whi + 4096 * NF; lo = g_Wlo + 4096 * NF; }
  const float4* s4 = (const float4*)src;
  f16x4* h4 = (f16x4*)hi;
  f16x4* l4 = (f16x4*)lo;
  for (int idx = i; idx < n4; idx += stride) {
    float4 v = s4[idx];
    f16x4 h, l;
    h.x = (f16)v.x; l.x = (f16)(v.x - (float)h.x);
    h.y = (f16)v.y; l.y = (f16)(v.y - (float)h.y);
    h.z = (f16)v.z; l.z = (f16)(v.z - (float)h.z);
    h.w = (f16)v.w; l.w = (f16)(v.w - (float)h.w);
    h4[idx] = h; l4[idx] = l;
  }
}

// ---------------- xp = A @ W^T + b  (split f16, 3 MFMA products) ----------------
__global__ __launch_bounds__(256, 1) void gemm_xp(
    const float* __restrict__ b_f, const float* __restrict__ b_b)
{
  const int d = blockIdx.z;
  const f16* WhiD = g_Whi + (size_t)d * (4096u * 2048u);
  const f16* WloD = g_Wlo + (size_t)d * (4096u * 2048u);
  const float* bias = d ? b_b : b_f;
  float* out = g_xp + (size_t)d * (4096u * 4096u);

  __shared__ f16 sAh[128 * 40];
  __shared__ f16 sAl[128 * 40];
  __shared__ f16 sWh[128 * 40];
  __shared__ f16 sWl[128 * 40];

  const int tid  = threadIdx.x;
  const int lane = tid & 63;
  const int wv   = tid >> 6;
  const int quad = lane >> 4;
  const int mrow = lane & 15;
  const int m0 = (wv & 1) * 64;
  const int n0 = (wv >> 1) * 64;
  const int bm = blockIdx.y, bn = blockIdx.x;

  f32x4 acc[4][4] = {};

  const int r0  = tid >> 2;
  const int seg = tid & 3;

  for (int kt = 0; kt < 2048; kt += 32) {
#pragma unroll
    for (int r = 0; r < 2; ++r) {
      int row = r * 64 + r0;
      size_t ga = (size_t)(bm * 128 + row) * 2048 + kt + seg * 8;
      size_t gw = (size_t)(bn * 128 + row) * 2048 + kt + seg * 8;
      int lidx = row * 40 + seg * 8;
      *(f16x8*)&sAh[lidx] = *(const f16x8*)&g_Ahi[ga];
      *(f16x8*)&sAl[lidx] = *(const f16x8*)&g_Alo[ga];
      *(f16x8*)&sWh[lidx] = *(const f16x8*)&WhiD[gw];
      *(f16x8*)&sWl[lidx] = *(const f16x8*)&WloD[gw];
    }
    __syncthreads();

    f16x8 ah[4], al[4], wh[4], wl[4];
#pragma unroll
    for (int mi = 0; mi < 4; ++mi) {
      int rowm = (m0 + mi * 16 + mrow) * 40 + quad * 8;
      ah[mi] = *(const f16x8*)&sAh[rowm];
      al[mi] = *(const f16x8*)&sAl[rowm];
    }
#pragma unroll
    for (int ni = 0; ni < 4; ++ni) {
      int rown = (n0 + ni * 16 + mrow) * 40 + quad * 8;
      wh[ni] = *(const f16x8*)&sWh[rown];
      wl[ni] = *(const f16x8*)&sWl[rown];
    }
#pragma unroll
    for (int mi = 0; mi < 4; ++mi)
#pragma unroll
      for (int ni = 0; ni < 4; ++ni) {
        acc[mi][ni] = __builtin_amdgcn_mfma_f32_16x16x32_f16(ah[mi], wh[ni], acc[mi][ni], 0, 0, 0);
        acc[mi][ni] = __builtin_amdgcn_mfma_f32_16x16x32_f16(ah[mi], wl[ni], acc[mi][ni], 0, 0, 0);
        acc[mi][ni] = __builtin_amdgcn_mfma_f32_16x16x32_f16(al[mi], wh[ni], acc[mi][ni], 0, 0, 0);
      }
    __syncthreads();
  }

#pragma unroll
  for (int ni = 0; ni < 4; ++ni) {
    int g = bn * 128 + n0 + ni * 16 + mrow;
    float bv = bias[g];
#pragma unroll
    for (int mi = 0; mi < 4; ++mi) {
#pragma unroll
      for (int r = 0; r < 4; ++r) {
        int t = bm * 128 + m0 + mi * 16 + quad * 4 + r;
        out[(size_t)t * 4096 + g] = acc[mi][ni][r] + bv;
      }
    }
  }
}

// ---------------- per-call ring reset (graph-replay safe) ----------------
__global__ void init_sync() {
  int i = blockIdx.x * blockDim.x + threadIdx.x;
  ((unsigned long long*)g_ring)[i] = 0ull;   // tag 0, h = 0.0f
}

// ---------------- persistent bidirectional LSTM ----------------
// 128 WGs x 1024 threads. dir = bid&1, wsl = bid>>1 (16 h-dims per WG).
// Waves 0..7 (tid<512): POLL the tagged ring with TWO loads in flight
// (alternating regs, s_waitcnt vmcnt(1)) -> observation quantum ~ RT/2
// instead of RT+sleep. R5 post-mortem: transaction count was NOT binding
// (4x fewer polls -> only 13%); the serial cost is poll-latency
// quantization, so this attacks the quantum directly.
// Wave 8 (tid 512..527): xp prefetch + cell update + publish — keeps
// poller waves' vmcnt queues clean (required for exact vmcnt(1) counting).
// GEMV: all 1024 threads, 1 row x 64 k each, weights VGPR-resident.
__global__ __launch_bounds__(1024) void lstm_persistent(
    const float* __restrict__ Whh_f, const float* __restrict__ Whh_b)
{
  const int bid = blockIdx.x;
  const int dir = bid & 1;
  const int wsl = bid >> 1;        // 0..63
  const int tid = threadIdx.x;
  const int r   = tid >> 4;        // local row 0..63 (gate = r>>4, jj = r&15)
  const int l16 = tid & 15;

  __shared__ float h_lds[1024];
  __shared__ float gates_lds[64];

  const float* Wd = dir ? Whh_b : Whh_f;

  // one-time weight load: row grow, cols 4*l16 + 64*j
  const int grow = (r >> 4) * 1024 + wsl * 16 + (r & 15);
  float4 w4[16];
#pragma unroll
  for (int j = 0; j < 16; ++j)
    w4[j] = *(const float4*)&Wd[(size_t)grow * 1024 + 4 * l16 + 64 * j];

  const float* xpd = g_xp + (size_t)dir * 4096u * 4096u;
  float* histd = g_hist + (size_t)dir * 4096u * 1024u;

  float c = 0.f;
  const int uu = tid - 512;        // update lane 0..15 for wave 8

  for (int t = 1; t <= 4096; ++t) {
    const int tau = dir ? (4096 - t) : (t - 1);

    // xp prefetch on wave 8 (off the pollers' vmcnt path)
    float xv0 = 0.f, xv1 = 0.f, xv2 = 0.f, xv3 = 0.f;
    if (uu >= 0 && uu < 16) {
      const float* px = xpd + (size_t)tau * 4096 + wsl * 16 + uu;
      xv0 = px[0]; xv1 = px[1024]; xv2 = px[2048]; xv3 = px[3072];
    }

    // poll ring for h_{t-1}: 512 loaders, 2 elems (16B) each, 2 loads in
    // flight alternating -> check older while newer flies.
    if (tid < 512) {
      const unsigned need = (unsigned)(t - 1);
      const unsigned long long* rs = &g_ring[dir][(t - 1) & 1][0] + 2 * tid;
      u32x4 qa, qb;
      asm volatile("global_load_dwordx4 %0, %1, off sc0 sc1" : "=v"(qa) : "v"(rs));
      asm volatile("global_load_dwordx4 %0, %1, off sc0 sc1" : "=v"(qb) : "v"(rs));
      float2 hv;
      for (;;) {
        asm volatile("s_waitcnt vmcnt(1)" : "+v"(qa) :: "memory");   // qa ready
        if (qa.y == need && qa.w == need) {
          hv.x = __uint_as_float(qa.x); hv.y = __uint_as_float(qa.z);
          break;
        }
        asm volatile("global_load_dwordx4 %0, %1, off sc0 sc1" : "=v"(qa) : "v"(rs));
        asm volatile("s_waitcnt vmcnt(1)" : "+v"(qb) :: "memory");   // qb ready
        if (qb.y == need && qb.w == need) {
          hv.x = __uint_as_float(qb.x); hv.y = __uint_as_float(qb.z);
          break;
        }
        asm volatile("global_load_dwordx4 %0, %1, off sc0 sc1" : "=v"(qb) : "v"(rs));
      }
      *(float2*)&h_lds[2 * tid] = hv;
    }
    __syncthreads();   // drains leftover in-flight polls (vmcnt(0) + barrier)

    // GEMV: 1 row x 64 k per thread, 4-way ILP partials
    float p0 = 0.f, p1 = 0.f, p2 = 0.f, p3 = 0.f;
#pragma unroll
    for (int j = 0; j < 16; j += 4) {
      float4 h0 = *(const float4*)&h_lds[4 * l16 + 64 * (j + 0)];
      float4 h1 = *(const float4*)&h_lds[4 * l16 + 64 * (j + 1)];
      float4 h2 = *(const float4*)&h_lds[4 * l16 + 64 * (j + 2)];
      float4 h3 = *(const float4*)&h_lds[4 * l16 + 64 * (j + 3)];
      p0 += w4[j+0].x*h0.x + w4[j+0].y*h0.y + w4[j+0].z*h0.z + w4[j+0].w*h0.w;
      p1 += w4[j+1].x*h1.x + w4[j+1].y*h1.y + w4[j+1].z*h1.z + w4[j+1].w*h1.w;
      p2 += w4[j+2].x*h2.x + w4[j+2].y*h2.y + w4[j+2].z*h2.z + w4[j+2].w*h2.w;
      p3 += w4[j+3].x*h3.x + w4[j+3].y*h3.y + w4[j+3].z*h3.z + w4[j+3].w*h3.w;
    }
    float acc = (p0 + p1) + (p2 + p3);
    acc += __shfl_xor(acc, 1);
    acc += __shfl_xor(acc, 2);
    acc += __shfl_xor(acc, 4);
    acc += __shfl_xor(acc, 8);
    if (l16 == 0) gates_lds[r] = acc;
    __syncthreads();

    // cell update + publish: wave 8, 16 h-dims
    if (uu >= 0 && uu < 16) {
      float gi = gates_lds[uu]      + xv0;
      float gf = gates_lds[16 + uu] + xv1;
      float gg = gates_lds[32 + uu] + xv2;
      float go = gates_lds[48 + uu] + xv3;
      float si = 1.f / (1.f + __expf(-gi));
      float sf = 1.f / (1.f + __expf(-gf));
      float so = 1.f / (1.f + __expf(-go));
      float tg = 1.f - 2.f / (1.f + __expf(2.f * gg));
      c = sf * c + si * tg;
      float th = 1.f - 2.f / (1.f + __expf(2.f * c));
      float h  = so * th;
      histd[(size_t)tau * 1024 + wsl * 16 + uu] = h;
      unsigned long long pk = ((unsigned long long)(unsigned)t << 32)
                            | (unsigned long long)__float_as_uint(h);
      __hip_atomic_store(&g_ring[dir][t & 1][wsl * 16 + uu], pk,
                         __ATOMIC_RELAXED, __HIP_MEMORY_SCOPE_AGENT);
    }
    // no trailing barrier: h_lds rewrites in t+1 are fenced by the post-poll
    // barrier; gates_lds rewrites by the post-GEMV barrier.
  }
}

// ---------------- feats = concat(h_f,h_b) @ W_lin^T + b_lin ----------------
__global__ __launch_bounds__(256, 1) void feats_kernel(
    const float* __restrict__ W_lin, const float* __restrict__ b_lin)
{
  const int tid = threadIdx.x;
  const int wv = tid >> 6, l = tid & 63;
  const int t0 = blockIdx.x * 16 + wv * 4;
  for (int it = 0; it < 4; ++it) {
    const int t = t0 + it;
    float hf[16], hbv[16];
#pragma unroll
    for (int i = 0; i < 16; ++i) hf[i]  = g_hist[(size_t)t * 1024 + l + 64 * i];
#pragma unroll
    for (int i = 0; i < 16; ++i) hbv[i] = g_hist[(size_t)(4096 + t) * 1024 + l + 64 * i];
#pragma unroll
    for (int tag = 0; tag < 10; ++tag) {
      float a = 0.f;
#pragma unroll
      for (int i = 0; i < 16; ++i) {
        a += W_lin[tag * 2048 + l + 64 * i] * hf[i];
        a += W_lin[tag * 2048 + 1024 + l + 64 * i] * hbv[i];
      }
      a += __shfl_xor(a, 32); a += __shfl_xor(a, 16); a += __shfl_xor(a, 8);
      a += __shfl_xor(a, 4);  a += __shfl_xor(a, 2);  a += __shfl_xor(a, 1);
      if (l == 0) g_feats[t * 10 + tag] = a + b_lin[tag];
    }
  }
}

// ---------------- Viterbi forward + backtrack ----------------
__global__ __launch_bounds__(64, 1) void viterbi_kernel(
    const float* __restrict__ trans, float* __restrict__ out)
{
  __shared__ unsigned char bps[4096 * 10];
  const int to = threadIdx.x;
  float tr[10];
#pragma unroll
  for (int f = 0; f < 10; ++f) tr[f] = (to < 10) ? trans[to * 10 + f] : 0.f;
  float fv = (to == 8) ? 0.f : -10000.f;   // START_TAG = 8

  float fbuf[8];
#pragma unroll
  for (int i = 0; i < 8; ++i) fbuf[i] = (to < 10) ? g_feats[i * 10 + to] : 0.f;

  for (int t = 0; t < 4096; t += 8) {
#pragma unroll
    for (int u = 0; u < 8; ++u) {
      const int tt = t + u;
      float m = -3.4e38f; int am = 0;
#pragma unroll
      for (int f = 0; f < 10; ++f) {
        float v = __shfl(fv, f) + tr[f];
        if (v > m) { m = v; am = f; }
      }
      float ft = fbuf[u];
      if (tt + 8 < 4096 && to < 10) fbuf[u] = g_feats[(tt + 8) * 10 + to];
      fv = m + ft;
      if (to < 10) bps[tt * 10 + to] = (unsigned char)am;
    }
  }
  __syncthreads();

  float term = fv + ((to < 10) ? trans[90 + to] : -3.4e38f);  // STOP_TAG row
  float best = -3.4e38f; int bl = 0;
#pragma unroll
  for (int f = 0; f < 10; ++f) {
    float v = __shfl(term, f);
    if (v > best) { best = v; bl = f; }
  }
  if (to == 0) {
    out[0] = best;
    int tag = bl;
    for (int t = 4095; t >= 0; --t) {
      out[1 + t] = (float)tag;
      tag = bps[t * 10 + tag];
    }
  }
}

// ---------------- launch ----------------
extern "C" void kernel_launch(void* const* d_in, const int* in_sizes, int n_in,
                              void* d_out, int out_size, void* d_ws, size_t ws_size,
                              hipStream_t stream)
{
  (void)in_sizes; (void)n_in; (void)out_size; (void)d_ws; (void)ws_size;
  const float* W_hh_f   = (const float*)d_in[2];
  const float* b_f      = (const float*)d_in[3];
  const float* W_hh_b   = (const float*)d_in[5];
  const float* b_b      = (const float*)d_in[6];
  const float* W_lin    = (const float*)d_in[7];
  const float* b_lin    = (const float*)d_in[8];
  const float* trans    = (const float*)d_in[9];

  cvt_split<<<1024, 256, 0, stream>>>((const float*)d_in[0], 0, 2097152);
  cvt_split<<<1024, 256, 0, stream>>>((const float*)d_in[1], 1, 2097152);
  cvt_split<<<1024, 256, 0, stream>>>((const float*)d_in[4], 2, 2097152);

  gemm_xp<<<dim3(32, 32, 2), 256, 0, stream>>>(b_f, b_b);

  init_sync<<<16, 256, 0, stream>>>();

  lstm_persistent<<<128, 1024, 0, stream>>>(W_hh_f, W_hh_b);

  feats_kernel<<<256, 256, 0, stream>>>(W_lin, b_lin);

  viterbi_kernel<<<1, 64, 0, stream>>>(trans, (float*)d_out);
}